// Round 4
// baseline (282.214 us; speedup 1.0000x reference)
//
#include <hip/hip_runtime.h>
#include <hip/hip_bf16.h>

#define N_NODES 40000
#define N_EDGES 640000
#define D_IN 512
#define D_OUT 128
#define NCOPY 8          // per-XCD cursor/bucket copies
#define CAPC 48          // slots per row per copy; P(overflow) ~1e-10 even degenerate
#define NB_SC 313        // scatter blocks: 640000 / (256*8) = 312.5
#define EPT 8
#define NB_GE 313        // gemm blocks: 1250 row-tiles / 4 waves
#define N_TILES 1250     // 40000 / 32 rows per wave-tile

typedef __attribute__((ext_vector_type(4))) float f32x4;
typedef __attribute__((ext_vector_type(8))) short bf16x8;
typedef __attribute__((ext_vector_type(4))) unsigned short us4;

static __device__ __forceinline__ unsigned short f2bf(float f) {
    unsigned int u = __float_as_uint(f);
    unsigned int r = u + 0x7fffu + ((u >> 16) & 1u);   // RNE
    return (unsigned short)(r >> 16);
}

// ---------------------------------------------------------------------------
// prep: blocks 0..31 pack W (f32 [128][512]) into bf16 MFMA B-fragment order:
//   entry e=(k,n,l): pb[e*8..+8] = bf16(w[n*16+(l&15)][k*32+(l>>4)*8 .. +8])
// blocks 32..1281 zero the 8 cursor copies (320000 ints).
// ---------------------------------------------------------------------------
__global__ __launch_bounds__(256) void prep_kernel(
    const float* __restrict__ w, unsigned short* __restrict__ pb,
    int* __restrict__ cursor)
{
    if (blockIdx.x < 32) {
        int e = blockIdx.x * 256 + threadIdx.x;        // 0..8191
        int l = e & 63, n = (e >> 6) & 7, k = e >> 9;
        int o = n * 16 + (l & 15);
        int kk = k * 32 + ((l >> 4) << 3);
        const float* src = w + (size_t)o * D_IN + kk;
        f32x4 v0 = *(const f32x4*)src;
        f32x4 v1 = *(const f32x4*)(src + 4);
        us4 h0, h1;
        #pragma unroll
        for (int q = 0; q < 4; q++) { h0[q] = f2bf(v0[q]); h1[q] = f2bf(v1[q]); }
        *(us4*)(pb + e * 8)     = h0;
        *(us4*)(pb + e * 8 + 4) = h1;
    } else {
        int i = (blockIdx.x - 32) * 256 + threadIdx.x;
        if (i < NCOPY * N_NODES) cursor[i] = 0;
    }
}

// ---------------------------------------------------------------------------
// fused: blocks [0, NB_SC) scatter edges into per-XCD bucket segments;
//        blocks [NB_SC, NB_SC+NB_GE) do the barrier-free MFMA GEMM.
// No LDS anywhere -> both kinds co-reside on every CU; scatter's atomic
// latency hides under GEMM loads/MFMA.
// ---------------------------------------------------------------------------
__global__ __launch_bounds__(256) void fused_kernel(
    const float* __restrict__ x, const unsigned short* __restrict__ pb,
    unsigned short* __restrict__ seq,
    const int* __restrict__ erow, const int* __restrict__ ecol,
    const float* __restrict__ eval, int* __restrict__ cursor,
    float2* __restrict__ bucket)
{
    if (blockIdx.x < NB_SC) {
        // ---- scatter: 8 edges/thread; cursor copy = this XCD (any 0-7 is
        // correct; XCD-match just keeps the atomic line in the local L2) ----
        unsigned int xcd;
        xcd = __builtin_amdgcn_s_getreg(20 | (0 << 6) | (7 << 11)) & 7;  // HW_REG_XCC_ID
        int* cur = cursor + (size_t)xcd * N_NODES;
        const int base = blockIdx.x * (256 * EPT) + threadIdx.x;
        int r[EPT], c[EPT];
        float v[EPT];
        bool ok[EPT];
        #pragma unroll
        for (int j = 0; j < EPT; j++) {
            int e = base + j * 256;
            ok[j] = e < N_EDGES;
            int es = ok[j] ? e : 0;
            r[j] = erow[es]; c[j] = ecol[es]; v[j] = eval[es];
        }
        int slot[EPT];
        #pragma unroll
        for (int j = 0; j < EPT; j++)
            if (ok[j]) slot[j] = atomicAdd(&cur[r[j]], 1);
        #pragma unroll
        for (int j = 0; j < EPT; j++)
            if (ok[j])
                bucket[((size_t)r[j] * NCOPY + xcd) * CAPC + slot[j]] =
                    make_float2(v[j], __int_as_float(c[j]));
        return;
    }

    // ---- GEMM: barrier-free. Each wave owns a 32-row tile; A from x with
    // 2-deep register prefetch; B from packed-W (L2-hot) per k-step. ----
    const int lane = threadIdx.x & 63;
    const int wv = threadIdx.x >> 6;
    const int tile = (blockIdx.x - NB_SC) * 4 + wv;
    if (tile >= N_TILES) return;
    const int r0 = tile * 32;
    const int arow = lane & 15;
    const int koff = (lane >> 4) << 3;

    f32x4 acc[2][8];
    #pragma unroll
    for (int m = 0; m < 2; m++)
        #pragma unroll
        for (int n = 0; n < 8; n++)
            acc[m][n] = f32x4{0.f, 0.f, 0.f, 0.f};

    f32x4 af[2][2][2];   // [buf][m][half] — static-indexed (k fully unrolled)
    const float* xa0 = x + (size_t)(r0 + arow) * D_IN + koff;
    const float* xa1 = x + (size_t)(r0 + 16 + arow) * D_IN + koff;

    #define LOAD_A(buf, k)  do {                                  \
        af[buf][0][0] = *(const f32x4*)(xa0 + (k) * 32);          \
        af[buf][0][1] = *(const f32x4*)(xa0 + (k) * 32 + 4);      \
        af[buf][1][0] = *(const f32x4*)(xa1 + (k) * 32);          \
        af[buf][1][1] = *(const f32x4*)(xa1 + (k) * 32 + 4);      \
    } while (0)

    LOAD_A(0, 0);
    LOAD_A(1, 1);

    #pragma unroll
    for (int k = 0; k < 16; k++) {
        const int cur = k & 1;
        bf16x8 a[2];
        #pragma unroll
        for (int m = 0; m < 2; m++) {
            us4 h0, h1;
            #pragma unroll
            for (int q = 0; q < 4; q++) {
                h0[q] = f2bf(af[cur][m][0][q]);
                h1[q] = f2bf(af[cur][m][1][q]);
            }
            a[m] = (bf16x8)(__attribute__((ext_vector_type(8))) unsigned short){
                h0[0], h0[1], h0[2], h0[3], h1[0], h1[1], h1[2], h1[3]};
        }
        if (k < 14) LOAD_A(cur, k + 2);   // refill the buffer just consumed
        bf16x8 b[8];
        #pragma unroll
        for (int n = 0; n < 8; n++)
            b[n] = *(const bf16x8*)(pb + (((k * 8 + n) * 64 + lane) << 3));
        #pragma unroll
        for (int n = 0; n < 8; n++)
            #pragma unroll
            for (int m = 0; m < 2; m++)
                acc[m][n] = __builtin_amdgcn_mfma_f32_16x16x32_bf16(a[m], b[n], acc[m][n], 0, 0, 0);
    }
    #undef LOAD_A

    // C/D layout: col=lane&15, row=(lane>>4)*4+reg  [measured m89]
    #pragma unroll
    for (int m = 0; m < 2; m++) {
        #pragma unroll
        for (int r = 0; r < 4; r++) {
            int grow = r0 + m * 16 + (lane >> 4) * 4 + r;
            #pragma unroll
            for (int n = 0; n < 8; n++) {
                int col = n * 16 + (lane & 15);
                seq[(size_t)grow * D_OUT + col] = f2bf(acc[m][n][r]);
            }
        }
    }
}

// ---------------------------------------------------------------------------
// agg: one wave per row; lane owns cols {2l, 2l+1}; walk the 8 copy-segments.
// ---------------------------------------------------------------------------
__global__ __launch_bounds__(256) void agg_kernel(
    const unsigned short* __restrict__ seq, const int* __restrict__ cursor,
    const float2* __restrict__ bucket, const float* __restrict__ bias,
    const float* __restrict__ alpha, float* __restrict__ out)
{
    const int row = blockIdx.x * 4 + (threadIdx.x >> 6);
    const int lane = threadIdx.x & 63;

    float a0 = 0.f, a1 = 0.f;
    #pragma unroll
    for (int c = 0; c < NCOPY; c++) {
        const int cnt = cursor[(size_t)c * N_NODES + row];
        const float2* b = bucket + ((size_t)row * NCOPY + c) * CAPC;
        int e = 0;
        for (; e + 4 <= cnt; e += 4) {
            float2 q0 = b[e], q1 = b[e + 1], q2 = b[e + 2], q3 = b[e + 3];
            unsigned int p0 = *(const unsigned int*)(seq + (size_t)__float_as_uint(q0.y) * D_OUT + lane * 2);
            unsigned int p1 = *(const unsigned int*)(seq + (size_t)__float_as_uint(q1.y) * D_OUT + lane * 2);
            unsigned int p2 = *(const unsigned int*)(seq + (size_t)__float_as_uint(q2.y) * D_OUT + lane * 2);
            unsigned int p3 = *(const unsigned int*)(seq + (size_t)__float_as_uint(q3.y) * D_OUT + lane * 2);
            a0 += q0.x * __uint_as_float(p0 << 16);
            a1 += q0.x * __uint_as_float(p0 & 0xffff0000u);
            a0 += q1.x * __uint_as_float(p1 << 16);
            a1 += q1.x * __uint_as_float(p1 & 0xffff0000u);
            a0 += q2.x * __uint_as_float(p2 << 16);
            a1 += q2.x * __uint_as_float(p2 & 0xffff0000u);
            a0 += q3.x * __uint_as_float(p3 << 16);
            a1 += q3.x * __uint_as_float(p3 & 0xffff0000u);
        }
        for (; e < cnt; ++e) {
            float2 q0 = b[e];
            unsigned int p0 = *(const unsigned int*)(seq + (size_t)__float_as_uint(q0.y) * D_OUT + lane * 2);
            a0 += q0.x * __uint_as_float(p0 << 16);
            a1 += q0.x * __uint_as_float(p0 & 0xffff0000u);
        }
    }
    float al = alpha[0];
    float2 bi = *(const float2*)(bias + lane * 2);
    float r0 = a0 + bi.x;
    float r1 = a1 + bi.y;
    r0 = r0 > 0.f ? r0 : al * r0;
    r1 = r1 > 0.f ? r1 : al * r1;
    *(float2*)(out + (size_t)row * D_OUT + lane * 2) = make_float2(r0, r1);
}

// ---------------------------------------------------------------------------
extern "C" void kernel_launch(void* const* d_in, const int* in_sizes, int n_in,
                              void* d_out, int out_size, void* d_ws, size_t ws_size,
                              hipStream_t stream)
{
    (void)in_sizes; (void)n_in; (void)out_size; (void)ws_size;
    const float* x     = (const float*)d_in[0];
    const float* w     = (const float*)d_in[1];
    const float* bias  = (const float*)d_in[2];
    const float* alpha = (const float*)d_in[3];
    const float* eval  = (const float*)d_in[4];
    const int*   erow  = (const int*)d_in[5];
    const int*   ecol  = (const int*)d_in[6];
    float* out = (float*)d_out;

    char* ws = (char*)d_ws;
    unsigned short* seq = (unsigned short*)ws;          // 10,240,000 B
    int*    cursor = (int*)(ws + 10240000);             //  1,280,000 B (8 copies)
    unsigned short* pb = (unsigned short*)(ws + 11520000); // 131,072 B packed W
    float2* bucket = (float2*)(ws + 11651072);          // 122,880,000 B (total ~134.5 MB)

    prep_kernel<<<1282, 256, 0, stream>>>(w, pb, cursor);
    fused_kernel<<<NB_SC + NB_GE, 256, 0, stream>>>(x, pb, seq, erow, ecol, eval, cursor, bucket);
    agg_kernel<<<N_NODES / 4, 256, 0, stream>>>(seq, cursor, bucket, bias, alpha, out);
}

// Round 5
// 225.124 us; speedup vs baseline: 1.2536x; 1.2536x over previous
//
#include <hip/hip_runtime.h>
#include <hip/hip_bf16.h>

#define N_NODES 40000
#define N_EDGES 640000
#define D_IN 512
#define D_OUT 128
#define NCOPY 8          // per-XCD cursor/bucket copies
#define CAPC 12          // slots per row per copy (Poisson(2) tail ~1e-7 w/ overflow net)
#define SLOTS (NCOPY * CAPC)   // 96 per row, 384 B contiguous
#define OVF_MAX 4096
#define NB_SC 313        // scatter blocks: 640000 / (256*8)
#define EPT 8
#define NB_GE 313        // gemm blocks
#define N_TILES 1250     // 40000 / 32 rows per wave
#define ZBLK 2048        // zeroing blocks in prep

typedef __attribute__((ext_vector_type(4))) float f32x4;
typedef __attribute__((ext_vector_type(8))) short bf16x8;
typedef __attribute__((ext_vector_type(4))) unsigned short us4;

static __device__ __forceinline__ unsigned short f2bf(float f) {
    unsigned int u = __float_as_uint(f);
    unsigned int r = u + 0x7fffu + ((u >> 16) & 1u);   // RNE
    return (unsigned short)(r >> 16);
}

// ---------------------------------------------------------------------------
// prep: blocks 0..31 pack W into MFMA B-fragment order (bf16);
//       blocks 32.. zero cursor+ovf+bucket (16.7 MB, int4 grid-stride).
// ---------------------------------------------------------------------------
__global__ __launch_bounds__(256) void prep_kernel(
    const float* __restrict__ w, unsigned short* __restrict__ pb,
    int4* __restrict__ zbase, int nz4)
{
    if (blockIdx.x < 32) {
        int e = blockIdx.x * 256 + threadIdx.x;        // 0..8191
        int l = e & 63, n = (e >> 6) & 7, k = e >> 9;
        int o = n * 16 + (l & 15);
        int kk = k * 32 + ((l >> 4) << 3);
        const float* src = w + (size_t)o * D_IN + kk;
        f32x4 v0 = *(const f32x4*)src;
        f32x4 v1 = *(const f32x4*)(src + 4);
        us4 h0, h1;
        #pragma unroll
        for (int q = 0; q < 4; q++) { h0[q] = f2bf(v0[q]); h1[q] = f2bf(v1[q]); }
        *(us4*)(pb + e * 8)     = h0;
        *(us4*)(pb + e * 8 + 4) = h1;
    } else {
        const int stride = ZBLK * 256;
        for (int i = (blockIdx.x - 32) * 256 + threadIdx.x; i < nz4; i += stride)
            zbase[i] = make_int4(0, 0, 0, 0);
    }
}

// ---------------------------------------------------------------------------
// fused: blocks [0, NB_SC) scatter; blocks [NB_SC, ..) barrier-free MFMA GEMM.
// ---------------------------------------------------------------------------
__global__ __launch_bounds__(256) void fused_kernel(
    const float* __restrict__ x, const unsigned short* __restrict__ pb,
    unsigned short* __restrict__ seq,
    const int* __restrict__ erow, const int* __restrict__ ecol,
    const float* __restrict__ eval, int* __restrict__ cursor,
    unsigned int* __restrict__ bucket, int* __restrict__ ovf_cnt,
    int4* __restrict__ ovf)
{
    if (blockIdx.x < NB_SC) {
        // scatter: 8 edges/thread; cursor copy = local XCD (any value 0-7 is
        // correct; matching keeps the atomic's line in the local L2)
        unsigned int xcd = __builtin_amdgcn_s_getreg(20 | (7 << 11)) & 7; // XCC_ID
        int* cur = cursor + (size_t)xcd * N_NODES;
        const int base = blockIdx.x * (256 * EPT) + threadIdx.x;
        int r[EPT], c[EPT];
        float v[EPT];
        bool ok[EPT];
        #pragma unroll
        for (int j = 0; j < EPT; j++) {
            int e = base + j * 256;
            ok[j] = e < N_EDGES;
            int es = ok[j] ? e : 0;
            r[j] = erow[es]; c[j] = ecol[es]; v[j] = eval[es];
        }
        int slot[EPT];
        #pragma unroll
        for (int j = 0; j < EPT; j++)
            if (ok[j]) slot[j] = atomicAdd(&cur[r[j]], 1);
        #pragma unroll
        for (int j = 0; j < EPT; j++) {
            if (!ok[j]) continue;
            if (slot[j] < CAPC) {
                bucket[(size_t)r[j] * SLOTS + xcd * CAPC + slot[j]] =
                    ((unsigned int)f2bf(v[j]) << 16) | (unsigned int)c[j];
            } else {
                int o = atomicAdd(ovf_cnt, 1);
                if (o < OVF_MAX)
                    ovf[o] = make_int4(r[j], c[j], __float_as_int(v[j]), 0);
            }
        }
        return;
    }

    // ---- GEMM: each wave owns a 32-row tile; A 2-deep prefetch; B from pb ----
    const int lane = threadIdx.x & 63;
    const int wv = threadIdx.x >> 6;
    const int tile = (blockIdx.x - NB_SC) * 4 + wv;
    if (tile >= N_TILES) return;
    const int r0 = tile * 32;
    const int arow = lane & 15;
    const int koff = (lane >> 4) << 3;

    f32x4 acc[2][8];
    #pragma unroll
    for (int m = 0; m < 2; m++)
        #pragma unroll
        for (int n = 0; n < 8; n++)
            acc[m][n] = f32x4{0.f, 0.f, 0.f, 0.f};

    f32x4 af[2][2][2];
    const float* xa0 = x + (size_t)(r0 + arow) * D_IN + koff;
    const float* xa1 = x + (size_t)(r0 + 16 + arow) * D_IN + koff;

    #define LOAD_A(buf, k)  do {                                  \
        af[buf][0][0] = *(const f32x4*)(xa0 + (k) * 32);          \
        af[buf][0][1] = *(const f32x4*)(xa0 + (k) * 32 + 4);      \
        af[buf][1][0] = *(const f32x4*)(xa1 + (k) * 32);          \
        af[buf][1][1] = *(const f32x4*)(xa1 + (k) * 32 + 4);      \
    } while (0)

    LOAD_A(0, 0);
    LOAD_A(1, 1);

    #pragma unroll
    for (int k = 0; k < 16; k++) {
        const int cur = k & 1;
        bf16x8 a[2];
        #pragma unroll
        for (int m = 0; m < 2; m++) {
            us4 h0, h1;
            #pragma unroll
            for (int q = 0; q < 4; q++) {
                h0[q] = f2bf(af[cur][m][0][q]);
                h1[q] = f2bf(af[cur][m][1][q]);
            }
            a[m] = (bf16x8)(__attribute__((ext_vector_type(8))) unsigned short){
                h0[0], h0[1], h0[2], h0[3], h1[0], h1[1], h1[2], h1[3]};
        }
        if (k < 14) LOAD_A(cur, k + 2);
        bf16x8 b[8];
        #pragma unroll
        for (int n = 0; n < 8; n++)
            b[n] = *(const bf16x8*)(pb + (((k * 8 + n) * 64 + lane) << 3));
        #pragma unroll
        for (int n = 0; n < 8; n++)
            #pragma unroll
            for (int m = 0; m < 2; m++)
                acc[m][n] = __builtin_amdgcn_mfma_f32_16x16x32_bf16(a[m], b[n], acc[m][n], 0, 0, 0);
    }
    #undef LOAD_A

    // C/D layout: col=lane&15, row=(lane>>4)*4+reg  [measured m89]
    #pragma unroll
    for (int m = 0; m < 2; m++) {
        #pragma unroll
        for (int r = 0; r < 4; r++) {
            int grow = r0 + m * 16 + (lane >> 4) * 4 + r;
            #pragma unroll
            for (int n = 0; n < 8; n++) {
                int col = n * 16 + (lane & 15);
                seq[(size_t)grow * D_OUT + col] = f2bf(acc[m][n][r]);
            }
        }
    }
}

// ---------------------------------------------------------------------------
// agg: one wave per row; lane owns cols {2l,2l+1}. Copy-interleaved slot walk:
// step s processes slot s of all 8 copies -> 8 independent coalesced seq reads
// in flight. Zeroed slots contribute exactly 0. Trip count = max copy count.
// ---------------------------------------------------------------------------
__global__ __launch_bounds__(256) void agg_kernel(
    const unsigned short* __restrict__ seq, const int* __restrict__ cursor,
    const unsigned int* __restrict__ bucket, const int* __restrict__ ovf_cnt,
    const int4* __restrict__ ovf, const float* __restrict__ bias,
    const float* __restrict__ alpha, float* __restrict__ out)
{
    const int row = blockIdx.x * 4 + (threadIdx.x >> 6);
    const int lane = threadIdx.x & 63;

    int mx = 0;
    #pragma unroll
    for (int c = 0; c < NCOPY; c++) {
        int n = cursor[(size_t)c * N_NODES + row];
        mx = n > mx ? n : mx;
    }
    mx = mx < CAPC ? mx : CAPC;

    const unsigned int* bk = bucket + (size_t)row * SLOTS;
    float a0 = 0.f, a1 = 0.f;
    for (int s = 0; s < mx; ++s) {
        #pragma unroll
        for (int c = 0; c < NCOPY; c++) {
            unsigned int q = bk[c * CAPC + s];
            float vv = __uint_as_float(q & 0xffff0000u);
            int col = q & 0xffff;
            unsigned int p = *(const unsigned int*)(seq + ((size_t)col << 7) + lane * 2);
            a0 += vv * __uint_as_float(p << 16);
            a1 += vv * __uint_as_float(p & 0xffff0000u);
        }
    }

    int on = *ovf_cnt;
    on = on < OVF_MAX ? on : OVF_MAX;
    for (int i = 0; i < on; ++i) {
        int4 t = ovf[i];
        if (t.x == row) {
            float vv = __int_as_float(t.z);
            unsigned int p = *(const unsigned int*)(seq + ((size_t)t.y << 7) + lane * 2);
            a0 += vv * __uint_as_float(p << 16);
            a1 += vv * __uint_as_float(p & 0xffff0000u);
        }
    }

    float al = alpha[0];
    float2 bi = *(const float2*)(bias + lane * 2);
    float r0 = a0 + bi.x;
    float r1 = a1 + bi.y;
    r0 = r0 > 0.f ? r0 : al * r0;
    r1 = r1 > 0.f ? r1 : al * r1;
    *(float2*)(out + (size_t)row * D_OUT + lane * 2) = make_float2(r0, r1);
}

// ---------------------------------------------------------------------------
extern "C" void kernel_launch(void* const* d_in, const int* in_sizes, int n_in,
                              void* d_out, int out_size, void* d_ws, size_t ws_size,
                              hipStream_t stream)
{
    (void)in_sizes; (void)n_in; (void)out_size; (void)ws_size;
    const float* x     = (const float*)d_in[0];
    const float* w     = (const float*)d_in[1];
    const float* bias  = (const float*)d_in[2];
    const float* alpha = (const float*)d_in[3];
    const float* eval  = (const float*)d_in[4];
    const int*   erow  = (const int*)d_in[5];
    const int*   ecol  = (const int*)d_in[6];
    float* out = (float*)d_out;

    char* ws = (char*)d_ws;
    unsigned short* seq = (unsigned short*)ws;              // 10,240,000 B
    unsigned short* pb  = (unsigned short*)(ws + 10240000); //    131,072 B
    int*  cursor  = (int*)(ws + 10371072);                  //  1,280,000 B (8 copies)
    int*  ovf_cnt = (int*)(ws + 11651072);                  //         16 B
    int4* ovf     = (int4*)(ws + 11651088);                 //     65,536 B
    unsigned int* bucket = (unsigned int*)(ws + 11716624);  // 15,360,000 B (tot ~27 MB)

    // zero region: cursor..bucket end = 16,705,552 B = 1,044,097 int4
    const int nz4 = 1044097;
    prep_kernel<<<32 + ZBLK, 256, 0, stream>>>(w, pb, (int4*)(ws + 10371072), nz4);
    fused_kernel<<<NB_SC + NB_GE, 256, 0, stream>>>(x, pb, seq, erow, ecol, eval,
                                                    cursor, bucket, ovf_cnt, ovf);
    agg_kernel<<<N_NODES / 4, 256, 0, stream>>>(seq, cursor, bucket, ovf_cnt, ovf,
                                                bias, alpha, out);
}

// Round 6
// 189.156 us; speedup vs baseline: 1.4920x; 1.1901x over previous
//
#include <hip/hip_runtime.h>
#include <hip/hip_bf16.h>

#define N_NODES 40000
#define N_EDGES 640000
#define D_IN 512
#define D_OUT 128
#define BM 128
#define BK 64
#define CAPC 32          // packed 4B slots per row (P(Poisson(16)>32)~1e-4, ovf net)
#define OVF_MAX 4096
#define NB_GE 313        // gemm blocks (128-row tiles)
#define NB_SC 625        // scatter blocks: 640000 / (256*4)
#define EPT 4

typedef __attribute__((ext_vector_type(4))) float f32x4;
typedef __attribute__((ext_vector_type(8))) short bf16x8;
typedef __attribute__((ext_vector_type(4))) unsigned short us4;

static __device__ __forceinline__ unsigned short f2bf(float f) {
    unsigned int u = __float_as_uint(f);
    unsigned int r = u + 0x7fffu + ((u >> 16) & 1u);   // RNE
    return (unsigned short)(r >> 16);
}

// ---------------------------------------------------------------------------
// prep: zero cursor + ovf_cnt + ovf + bucket (5.35 MB, int4 grid-stride)
// ---------------------------------------------------------------------------
__global__ __launch_bounds__(256) void prep_kernel(int4* __restrict__ zbase, int nz4)
{
    const int stride = 512 * 256;
    for (int i = blockIdx.x * 256 + threadIdx.x; i < nz4; i += stride)
        zbase[i] = make_int4(0, 0, 0, 0);
}

// ---------------------------------------------------------------------------
// fused: blocks [0, NB_GE) = LDS-tiled MFMA GEMM (R3-proven);
//        blocks [NB_GE, NB_GE+NB_SC) = single-cursor bucket scatter.
// ---------------------------------------------------------------------------
__global__ __launch_bounds__(256) void fused_kernel(
    const float* __restrict__ x, const float* __restrict__ w,
    unsigned short* __restrict__ seq,
    const int* __restrict__ erow, const int* __restrict__ ecol,
    const float* __restrict__ eval, int* __restrict__ cursor,
    unsigned int* __restrict__ bucket, int* __restrict__ ovf_cnt,
    int4* __restrict__ ovf)
{
    if (blockIdx.x >= NB_GE) {
        // ---- scatter: 4 edges/thread; slot via global atomic (memory-side) ----
        const int base = (blockIdx.x - NB_GE) * (256 * EPT) + threadIdx.x;
        int r[EPT], c[EPT];
        float v[EPT];
        #pragma unroll
        for (int j = 0; j < EPT; j++) {
            int e = base + j * 256;
            r[j] = erow[e]; c[j] = ecol[e]; v[j] = eval[e];
        }
        int slot[EPT];
        #pragma unroll
        for (int j = 0; j < EPT; j++) slot[j] = atomicAdd(&cursor[r[j]], 1);
        #pragma unroll
        for (int j = 0; j < EPT; j++) {
            if (slot[j] < CAPC) {
                bucket[(size_t)r[j] * CAPC + slot[j]] =
                    ((unsigned int)f2bf(v[j]) << 16) | (unsigned int)c[j];
            } else {
                int o = atomicAdd(ovf_cnt, 1);
                if (o < OVF_MAX)
                    ovf[o] = make_int4(r[j], c[j], __float_as_int(v[j]), 0);
            }
        }
        return;
    }

    // ---- GEMM: seq[n][o] = sum_i x[n][i]*w[o][i], bf16 out (R3-proven) ----
    __shared__ unsigned short As[BM * BK];     // 16 KB
    __shared__ unsigned short Bs[D_OUT * BK];  // 16 KB

    const int tid = threadIdx.x;
    const int lane = tid & 63;
    const int wv = tid >> 6;
    const int block_row = blockIdx.x * BM;
    const int srow = tid >> 3;               // 0..31
    const int scol = (tid & 7) * 8;          // 0..56

    f32x4 ra[4][2], rb[4][2];                // prefetch regs

    auto issue_loads = [&](int k0) {
        #pragma unroll
        for (int p = 0; p < 4; ++p) {
            int gr = block_row + srow + p * 32; if (gr >= N_NODES) gr = N_NODES - 1;
            const float* sa = x + (size_t)gr * D_IN + k0 + scol;
            ra[p][0] = *(const f32x4*)sa;
            ra[p][1] = *(const f32x4*)(sa + 4);
            const float* sb = w + (size_t)(srow + p * 32) * D_IN + k0 + scol;
            rb[p][0] = *(const f32x4*)sb;
            rb[p][1] = *(const f32x4*)(sb + 4);
        }
    };

    f32x4 acc[2][8];
    #pragma unroll
    for (int i = 0; i < 2; i++)
        #pragma unroll
        for (int j = 0; j < 8; j++)
            acc[i][j] = f32x4{0.f, 0.f, 0.f, 0.f};

    issue_loads(0);

    for (int kt = 0; kt < D_IN / BK; ++kt) {
        __syncthreads();
        #pragma unroll
        for (int p = 0; p < 4; ++p) {
            int r = srow + p * 32;
            us4 h0, h1, g0, g1;
            #pragma unroll
            for (int q = 0; q < 4; q++) {
                h0[q] = f2bf(ra[p][0][q]); h1[q] = f2bf(ra[p][1][q]);
                g0[q] = f2bf(rb[p][0][q]); g1[q] = f2bf(rb[p][1][q]);
            }
            int off = (r * (BK * 2) + scol * 2) ^ ((r & 7) << 4);
            *(us4*)((char*)As + off)     = h0;
            *(us4*)((char*)As + off + 8) = h1;
            *(us4*)((char*)Bs + off)     = g0;
            *(us4*)((char*)Bs + off + 8) = g1;
        }
        if (kt < D_IN / BK - 1) issue_loads((kt + 1) * BK);  // overlap w/ MFMA
        __syncthreads();

        #pragma unroll
        for (int ks = 0; ks < 2; ++ks) {
            const int kb = ks * 32 + (lane >> 4) * 8;
            bf16x8 a[2], b[8];
            #pragma unroll
            for (int m = 0; m < 2; m++) {
                int r = wv * 32 + m * 16 + (lane & 15);
                int off = (r * (BK * 2) + kb * 2) ^ ((r & 7) << 4);
                a[m] = *(const bf16x8*)((const char*)As + off);
            }
            #pragma unroll
            for (int n = 0; n < 8; n++) {
                int r = n * 16 + (lane & 15);
                int off = (r * (BK * 2) + kb * 2) ^ ((r & 7) << 4);
                b[n] = *(const bf16x8*)((const char*)Bs + off);
            }
            #pragma unroll
            for (int m = 0; m < 2; m++)
                #pragma unroll
                for (int n = 0; n < 8; n++)
                    acc[m][n] = __builtin_amdgcn_mfma_f32_16x16x32_bf16(a[m], b[n], acc[m][n], 0, 0, 0);
        }
    }

    // C/D layout: col=lane&15, row=(lane>>4)*4+reg  [measured m89]
    #pragma unroll
    for (int m = 0; m < 2; m++) {
        #pragma unroll
        for (int r = 0; r < 4; r++) {
            int grow = block_row + wv * 32 + m * 16 + (lane >> 4) * 4 + r;
            if (grow < N_NODES) {
                #pragma unroll
                for (int n = 0; n < 8; n++) {
                    int col = n * 16 + (lane & 15);
                    seq[(size_t)grow * D_OUT + col] = f2bf(acc[m][n][r]);
                }
            }
        }
    }
}

// ---------------------------------------------------------------------------
// agg: one wave per row; lane owns cols {2l,2l+1}. 8-wide slot chunks; zeroed
// slots contribute exact 0 so chunks may overrun cnt (never past CAPC).
// ---------------------------------------------------------------------------
__global__ __launch_bounds__(256) void agg_kernel(
    const unsigned short* __restrict__ seq, const int* __restrict__ cursor,
    const unsigned int* __restrict__ bucket, const int* __restrict__ ovf_cnt,
    const int4* __restrict__ ovf, const float* __restrict__ bias,
    const float* __restrict__ alpha, float* __restrict__ out)
{
    const int row = blockIdx.x * 4 + (threadIdx.x >> 6);
    const int lane = threadIdx.x & 63;

    int cnt = cursor[row];
    int mx = cnt < CAPC ? cnt : CAPC;
    const unsigned int* bk = bucket + (size_t)row * CAPC;

    float a0 = 0.f, a1 = 0.f;
    for (int s = 0; s < mx; s += 8) {        // chunk of 8, overrun-safe
        #pragma unroll
        for (int j = 0; j < 8; j++) {
            unsigned int q = bk[s + j];
            float vv = __uint_as_float(q & 0xffff0000u);
            int col = q & 0xffff;
            unsigned int p = *(const unsigned int*)(seq + ((size_t)col << 7) + lane * 2);
            a0 += vv * __uint_as_float(p << 16);
            a1 += vv * __uint_as_float(p & 0xffff0000u);
        }
    }

    int on = *ovf_cnt;
    on = on < OVF_MAX ? on : OVF_MAX;
    for (int i = 0; i < on; ++i) {
        int4 t = ovf[i];
        if (t.x == row) {
            float vv = __int_as_float(t.z);
            unsigned int p = *(const unsigned int*)(seq + ((size_t)t.y << 7) + lane * 2);
            a0 += vv * __uint_as_float(p << 16);
            a1 += vv * __uint_as_float(p & 0xffff0000u);
        }
    }

    float al = alpha[0];
    float2 bi = *(const float2*)(bias + lane * 2);
    float r0 = a0 + bi.x;
    float r1 = a1 + bi.y;
    r0 = r0 > 0.f ? r0 : al * r0;
    r1 = r1 > 0.f ? r1 : al * r1;
    *(float2*)(out + (size_t)row * D_OUT + lane * 2) = make_float2(r0, r1);
}

// ---------------------------------------------------------------------------
extern "C" void kernel_launch(void* const* d_in, const int* in_sizes, int n_in,
                              void* d_out, int out_size, void* d_ws, size_t ws_size,
                              hipStream_t stream)
{
    (void)in_sizes; (void)n_in; (void)out_size; (void)ws_size;
    const float* x     = (const float*)d_in[0];
    const float* w     = (const float*)d_in[1];
    const float* bias  = (const float*)d_in[2];
    const float* alpha = (const float*)d_in[3];
    const float* eval  = (const float*)d_in[4];
    const int*   erow  = (const int*)d_in[5];
    const int*   ecol  = (const int*)d_in[6];
    float* out = (float*)d_out;

    char* ws = (char*)d_ws;
    unsigned short* seq  = (unsigned short*)ws;             // 10,240,000 B
    int*  cursor  = (int*)(ws + 10240000);                  //    160,000 B
    int*  ovf_cnt = (int*)(ws + 10400000);                  //         16 B
    int4* ovf     = (int4*)(ws + 10400016);                 //     65,536 B
    unsigned int* bucket = (unsigned int*)(ws + 10465552);  //  5,120,000 B (tot ~15.6 MB)

    // zero region: cursor..bucket end = 5,345,552 B = 334,097 int4
    const int nz4 = 334097;
    prep_kernel<<<512, 256, 0, stream>>>((int4*)(ws + 10240000), nz4);
    fused_kernel<<<NB_GE + NB_SC, 256, 0, stream>>>(x, w, seq, erow, ecol, eval,
                                                    cursor, bucket, ovf_cnt, ovf);
    agg_kernel<<<N_NODES / 4, 256, 0, stream>>>(seq, cursor, bucket, ovf_cnt, ovf,
                                                bias, alpha, out);
}